// Round 1
// baseline (94.038 us; speedup 1.0000x reference)
//
#include <hip/hip_runtime.h>
#include <math.h>

// Alignment (Kabsch) kernel:
//   H[b] = fx[b]^T fy[b]  (3x3, reduce over C=1024 points)
//   R[b] = (U Vh)^T  == transpose of orthogonal polar factor of H[b]
//   S[b][d] = ||fy[b,:,d]|| / ||fx[b,:,d]||
// Polar factor computed by scaled Newton iteration in f64 (unique for
// invertible H; identical to v @ u^T from SVD, including det=-1 cases).

namespace {
constexpr int THREADS = 256;
constexpr int FLOATS_PER_BATCH = 1024 * 3;  // 3072 floats = 768 float4
}

__global__ __launch_bounds__(THREADS)
void align_kernel(const float* __restrict__ fx,
                  const float* __restrict__ fy,
                  float* __restrict__ out,
                  int batches)
{
    const int b = blockIdx.x;
    const int t = threadIdx.x;

    const float4* fx4 = reinterpret_cast<const float4*>(fx + (size_t)b * FLOATS_PER_BATCH);
    const float4* fy4 = reinterpret_cast<const float4*>(fy + (size_t)b * FLOATS_PER_BATCH);

    // Each thread owns 4 consecutive points = 12 floats = 3 float4 (point-aligned: lcm(3,4)=12).
    float lx[12], ly[12];
    {
        float4 a0 = fx4[3 * t + 0], a1 = fx4[3 * t + 1], a2 = fx4[3 * t + 2];
        float4 b0 = fy4[3 * t + 0], b1 = fy4[3 * t + 1], b2 = fy4[3 * t + 2];
        lx[0] = a0.x; lx[1] = a0.y; lx[2]  = a0.z; lx[3]  = a0.w;
        lx[4] = a1.x; lx[5] = a1.y; lx[6]  = a1.z; lx[7]  = a1.w;
        lx[8] = a2.x; lx[9] = a2.y; lx[10] = a2.z; lx[11] = a2.w;
        ly[0] = b0.x; ly[1] = b0.y; ly[2]  = b0.z; ly[3]  = b0.w;
        ly[4] = b1.x; ly[5] = b1.y; ly[6]  = b1.z; ly[7]  = b1.w;
        ly[8] = b2.x; ly[9] = b2.y; ly[10] = b2.z; ly[11] = b2.w;
    }

    // v[0..8]  = H[d][e] partials (row-major d*3+e)
    // v[9..11] = sum fx^2 per d ; v[12..14] = sum fy^2 per d
    float v[15];
#pragma unroll
    for (int i = 0; i < 15; ++i) v[i] = 0.0f;

#pragma unroll
    for (int k = 0; k < 4; ++k) {
        float px0 = lx[3 * k + 0], px1 = lx[3 * k + 1], px2 = lx[3 * k + 2];
        float py0 = ly[3 * k + 0], py1 = ly[3 * k + 1], py2 = ly[3 * k + 2];
        v[0] += px0 * py0; v[1] += px0 * py1; v[2] += px0 * py2;
        v[3] += px1 * py0; v[4] += px1 * py1; v[5] += px1 * py2;
        v[6] += px2 * py0; v[7] += px2 * py1; v[8] += px2 * py2;
        v[9]  += px0 * px0; v[10] += px1 * px1; v[11] += px2 * px2;
        v[12] += py0 * py0; v[13] += py1 * py1; v[14] += py2 * py2;
    }

    // Wave (64-lane) butterfly-free down-reduction.
#pragma unroll
    for (int i = 0; i < 15; ++i) {
#pragma unroll
        for (int s = 32; s > 0; s >>= 1) v[i] += __shfl_down(v[i], s, 64);
    }

    __shared__ float red[4][15];
    const int wave = t >> 6;
    const int lane = t & 63;
    if (lane == 0) {
#pragma unroll
        for (int i = 0; i < 15; ++i) red[wave][i] = v[i];
    }
    __syncthreads();

    if (t == 0) {
        float tot[15];
#pragma unroll
        for (int i = 0; i < 15; ++i)
            tot[i] = red[0][i] + red[1][i] + red[2][i] + red[3][i];

        // ---- Polar decomposition of H (3x3) via scaled Newton, f64 ----
        double Q[9];
        double nf = 0.0;
#pragma unroll
        for (int i = 0; i < 9; ++i) { Q[i] = (double)tot[i]; nf += Q[i] * Q[i]; }
        double s0 = (nf > 0.0) ? 1.0 / sqrt(nf) : 1.0;
#pragma unroll
        for (int i = 0; i < 9; ++i) Q[i] *= s0;

        for (int it = 0; it < 9; ++it) {
            // Cofactor matrix C (so Q^{-T} = C / det)
            double C0 = Q[4] * Q[8] - Q[5] * Q[7];
            double C1 = Q[5] * Q[6] - Q[3] * Q[8];
            double C2 = Q[3] * Q[7] - Q[4] * Q[6];
            double C3 = Q[2] * Q[7] - Q[1] * Q[8];
            double C4 = Q[0] * Q[8] - Q[2] * Q[6];
            double C5 = Q[1] * Q[6] - Q[0] * Q[7];
            double C6 = Q[1] * Q[5] - Q[2] * Q[4];
            double C7 = Q[2] * Q[3] - Q[0] * Q[5];
            double C8 = Q[0] * Q[4] - Q[1] * Q[3];
            double det = Q[0] * C0 + Q[1] * C1 + Q[2] * C2;
            double ad = fabs(det);
            if (ad < 1e-300) { det = (det < 0.0) ? -1e-300 : 1e-300; ad = 1e-300; }
            double nq = Q[0]*Q[0]+Q[1]*Q[1]+Q[2]*Q[2]+Q[3]*Q[3]+Q[4]*Q[4]
                      + Q[5]*Q[5]+Q[6]*Q[6]+Q[7]*Q[7]+Q[8]*Q[8];
            double nc = C0*C0+C1*C1+C2*C2+C3*C3+C4*C4+C5*C5+C6*C6+C7*C7+C8*C8;
            // lambda = sqrt(||Q^{-1}||_F / ||Q||_F),  ||Q^{-1}||_F = sqrt(nc)/|det|
            double lam = sqrt(sqrt(nc) / (ad * sqrt(nq)));
            double hl = 0.5 * lam;
            double g  = 0.5 / (lam * det);
            double N0 = hl * Q[0] + g * C0;
            double N1 = hl * Q[1] + g * C1;
            double N2 = hl * Q[2] + g * C2;
            double N3 = hl * Q[3] + g * C3;
            double N4 = hl * Q[4] + g * C4;
            double N5 = hl * Q[5] + g * C5;
            double N6 = hl * Q[6] + g * C6;
            double N7 = hl * Q[7] + g * C7;
            double N8 = hl * Q[8] + g * C8;
            Q[0]=N0; Q[1]=N1; Q[2]=N2; Q[3]=N3; Q[4]=N4; Q[5]=N5; Q[6]=N6; Q[7]=N7; Q[8]=N8;
        }

        // R = Q^T  (row-major [3][3])
        float* Rout = out + (size_t)b * 9;
        Rout[0] = (float)Q[0]; Rout[1] = (float)Q[3]; Rout[2] = (float)Q[6];
        Rout[3] = (float)Q[1]; Rout[4] = (float)Q[4]; Rout[5] = (float)Q[7];
        Rout[6] = (float)Q[2]; Rout[7] = (float)Q[5]; Rout[8] = (float)Q[8];

        // S[d] = sqrt(sum fy^2 / sum fx^2)
        float* Sout = out + (size_t)batches * 9 + (size_t)b * 3;
        Sout[0] = sqrtf(tot[12] / tot[9]);
        Sout[1] = sqrtf(tot[13] / tot[10]);
        Sout[2] = sqrtf(tot[14] / tot[11]);
    }
}

extern "C" void kernel_launch(void* const* d_in, const int* in_sizes, int n_in,
                              void* d_out, int out_size, void* d_ws, size_t ws_size,
                              hipStream_t stream) {
    const float* fx = (const float*)d_in[0];
    const float* fy = (const float*)d_in[1];
    float* out = (float*)d_out;
    const int batches = in_sizes[0] / FLOATS_PER_BATCH;  // 16384
    align_kernel<<<batches, THREADS, 0, stream>>>(fx, fy, out, batches);
}